// Round 8
// baseline (794.502 us; speedup 1.0000x reference)
//
#include <hip/hip_runtime.h>
#include <hip/hip_bf16.h>
#include <hip/hip_fp16.h>

#define NN 50000
#define NE 400000
#define NBLK 196   // ceil(NN/256)
#define PST 544    // P row stride (1088 B = 64*17, breaks power-of-2 aliasing)

typedef unsigned short u16;
typedef unsigned int u32;
typedef __attribute__((ext_vector_type(8))) short short8;
typedef __attribute__((ext_vector_type(4))) float f32x4;
typedef __attribute__((ext_vector_type(4))) unsigned short u16x4;
typedef __attribute__((ext_vector_type(2))) _Float16 h2;
typedef __attribute__((ext_vector_type(16))) unsigned int u32x16;

typedef __attribute__((address_space(1))) const void as1_void;
typedef __attribute__((address_space(3))) void as3_void;

static __device__ __forceinline__ float bf2f(u16 u) {
    return __uint_as_float(((u32)u) << 16);
}
static __device__ __forceinline__ float bf2f_lo(u32 u) {
    return __uint_as_float(u << 16);
}
static __device__ __forceinline__ float bf2f_hi(u32 u) {
    return __uint_as_float(u & 0xffff0000u);
}
static __device__ __forceinline__ u16 f2bf(float f) {
    u32 x = __float_as_uint(f);
    x += 0x7fffu + ((x >> 16) & 1u);
    return (u16)(x >> 16);
}
static __device__ __forceinline__ u32 packbf2(float a, float b) {
    return ((u32)f2bf(b) << 16) | (u32)f2bf(a);
}
static __device__ __forceinline__ u32 packh2(float a, float b) {
    return ((u32)__half_as_ushort(__float2half(b)) << 16) |
           (u32)__half_as_ushort(__float2half(a));
}

static __device__ __forceinline__ void gload_lds16(const u16* g, u16* l) {
    __builtin_amdgcn_global_load_lds((as1_void*)g, (as3_void*)l, 16, 0, 0);
}

// ---------------------------------------------------------------------------
// bf16 GEMM: C[M,N] = A[M,K] @ Bt[N,K]^T, epilogue (+bias)(relu), bf16 out.
// m97 structure: 128x128 tile, BK=32, 4 waves, 4x4 16x16x32 frags.
// ---------------------------------------------------------------------------
__global__ __launch_bounds__(256) void gemm_bt(
    const u16* __restrict__ A, int lda,
    const u16* __restrict__ Bt,
    u16* __restrict__ C, int ldc,
    int M, int K,
    const float* __restrict__ bias,
    int relu)
{
    __shared__ u16 As[128 * 32];
    __shared__ u16 Bs[128 * 32];

    const int t = threadIdx.x;
    const int w = t >> 6;
    const int lane = t & 63;
    const int quad = lane >> 4;
    const int l15 = lane & 15;
    const int tile_m = blockIdx.x * 128;
    const int tile_n = blockIdx.y * 128;
    const int wm = (w >> 1) * 64;
    const int wn = (w & 1) * 64;

    f32x4 acc[4][4];
#pragma unroll
    for (int r = 0; r < 4; ++r)
#pragma unroll
        for (int c = 0; c < 4; ++c)
            acc[r][c] = (f32x4){0.f, 0.f, 0.f, 0.f};

    int ar0 = tile_m + (t >> 2);      if (ar0 > M - 1) ar0 = M - 1;
    int ar1 = tile_m + 64 + (t >> 2); if (ar1 > M - 1) ar1 = M - 1;
    const int br0 = tile_n + (t >> 2);
    const int br1 = tile_n + 64 + (t >> 2);
    const int koff = (t & 3) * 8;

    u16* lAs0 = As + w * 512;
    u16* lAs1 = As + 2048 + w * 512;
    u16* lBs0 = Bs + w * 512;
    u16* lBs1 = Bs + 2048 + w * 512;

    const u16* Arow0 = A + (size_t)ar0 * lda + koff;
    const u16* Arow1 = A + (size_t)ar1 * lda + koff;
    const u16* Brow0 = Bt + (size_t)br0 * K + koff;
    const u16* Brow1 = Bt + (size_t)br1 * K + koff;

    for (int k0 = 0; k0 < K; k0 += 32) {
        gload_lds16(Arow0 + k0, lAs0);
        gload_lds16(Arow1 + k0, lAs1);
        gload_lds16(Brow0 + k0, lBs0);
        gload_lds16(Brow1 + k0, lBs1);
        __syncthreads();

        short8 af[4], bfr[4];
#pragma unroll
        for (int r = 0; r < 4; ++r)
            af[r] = *(const short8*)&As[(wm + r * 16 + l15) * 32 + quad * 8];
#pragma unroll
        for (int c = 0; c < 4; ++c)
            bfr[c] = *(const short8*)&Bs[(wn + c * 16 + l15) * 32 + quad * 8];
#pragma unroll
        for (int r = 0; r < 4; ++r)
#pragma unroll
            for (int c = 0; c < 4; ++c)
                acc[r][c] = __builtin_amdgcn_mfma_f32_16x16x32_bf16(af[r], bfr[c], acc[r][c], 0, 0, 0);
        __syncthreads();
    }

#pragma unroll
    for (int r = 0; r < 4; ++r) {
#pragma unroll
        for (int c = 0; c < 4; ++c) {
            const int coln = tile_n + wn + c * 16 + l15;
            const float bv = bias ? bias[coln] : 0.0f;
#pragma unroll
            for (int i = 0; i < 4; ++i) {
                const int row = tile_m + wm + r * 16 + quad * 4 + i;
                if (row < M) {
                    float v = acc[r][c][i] + bv;
                    if (relu) v = fmaxf(v, 0.f);
                    C[(size_t)row * ldc + coln] = f2bf(v);
                }
            }
        }
    }
}

// ---------------------------------------------------------------------------
// Fused edge message + mean aggregation. TWO waves per node, 128 cols each
// (2 cols/lane as packed-bf16 u32).
//
// Ledger R0-R7: duration pinned at ~103us across every weight path; VGPR
// stuck at 28 (ARCH VGPRs only) while ~120 VALU/edge issue vs ~47 needed.
// Diagnosis: the wave-uniform 32-dword eattr block lives in AGPRs (unified
// file, not shown in VGPR_Count) and every fdot2 operand read is a
// v_accvgpr copy -> the persistent ~2.5x VALU inflation. R7's LDS-traffic
// halving proved weights/LDS were never the bound.
// Fix: eattr -> REAL SGPRs. It is wave-uniform, so s_load_dwordx16 on the
// scalar pipe (zero VALU) holds it in the ~half-empty SGPR file, and
// v_dot2_f32_f16 reads one SGPR source directly (inline asm pins the "s"
// operand class). VGPR live set collapses to ~20 -> fits the 28-reg budget,
// no AGPR traffic. Weights stay in LDS with read-once-dot-two-edges
// amortization (R7). lgkmcnt(0) + sched_barrier(0) fence the asm s_loads
// before consumption (rule: compiler hoists reg-only asm past waitcnt).
// P rows [Ps(256)|Pd(256)], stride PST. agg -> Z[:,0:256] (stride 512).
// ---------------------------------------------------------------------------
__global__ __launch_bounds__(256) void edge_agg_fused(
    const u16* __restrict__ P,
    const u32* __restrict__ eattr_p32,
    const u32* __restrict__ WePk,
    const int* __restrict__ row_start,
    const int* __restrict__ src_perm,
    const float* __restrict__ inv_deg,
    u16* __restrict__ aggZ)
{
    __shared__ u32 Wlds[4096];   // 16 KB: same linear layout as WePk

    const int t = threadIdx.x;
    {   // stage weights: 4 rounds x (4 waves x 64 lanes x 16 B) = 16 KB
        const u16* Wg = (const u16*)WePk;
        u16* Wl = (u16*)Wlds;
        const int wv = t >> 6;
        const int ln = t & 63;
#pragma unroll
        for (int r = 0; r < 4; ++r)
            gload_lds16(Wg + r * 2048 + wv * 512 + ln * 8,
                        Wl + r * 2048 + wv * 512);
    }
    __syncthreads();

    const int wid = (int)((blockIdx.x * 256 + t) >> 6);
    const int node = wid >> 1;
    const int half = wid & 1;
    const int lane = t & 63;
    const int coff = half * 128 + lane * 2;
    if (node >= NN) return;   // never true at AGG_BLK=25000; after barrier

    const u32 pdu = *(const u32*)(P + (size_t)node * PST + 256 + coff);
    const float pb0 = bf2f_lo(pdu);
    const float pb1 = bf2f_hi(pdu);

    float acc0 = 0.f, acc1 = 0.f;
    const int s0r = row_start[node], s1r = row_start[node + 1];

    if (s1r > s0r) {
        const int jlast = s1r - 1;
        const unsigned long long ebase =
            (unsigned long long)(uintptr_t)eattr_p32;

#define PSLD(ps, jj) do {                                                 \
        int js_ = __builtin_amdgcn_readfirstlane(                         \
            ((jj) < jlast) ? (jj) : jlast);                               \
        int ss_ = src_perm[js_];                                          \
        ps = *(const u32*)(P + (size_t)ss_ * PST + coff);                 \
    } while (0)

        u32 psA, psB;
        PSLD(psA, s0r);
        PSLD(psB, s0r + 1);

        for (int j = s0r; j < s1r; j += 2) {
            // eattr rows for both edges -> SGPR tuples via scalar pipe.
            const u32 offA = (u32)__builtin_amdgcn_readfirstlane(j) << 6;
            const u32 offB = (u32)__builtin_amdgcn_readfirstlane(
                (j + 1 < jlast) ? j + 1 : jlast) << 6;
            u32x16 ea, eb;
            asm volatile("s_load_dwordx16 %0, %2, %3\n\t"
                         "s_load_dwordx16 %1, %2, %4"
                         : "=s"(ea), "=s"(eb)
                         : "s"(ebase), "s"(offA), "s"(offB));

            // next trip's gathers issued under the s_load latency
            u32 psC, psD;
            PSLD(psC, j + 2);
            PSLD(psD, j + 3);

            asm volatile("s_waitcnt lgkmcnt(0)" ::: "memory");
            __builtin_amdgcn_sched_barrier(0);

            float q0A = pb0, q1A = pb1, q0B = pb0, q1B = pb1;
            // each weight uint2 read ONCE from LDS, dotted against BOTH
            // edges; eattr operands pinned to SGPR class (1 SGPR/VOP3P ok)
#define KP(idx)                                                           \
            {                                                             \
                uint2 wk = *(const uint2*)(Wlds + idx * 256 + coff);      \
                asm("v_dot2_f32_f16 %0, %4, %6, %0\n\t"                   \
                    "v_dot2_f32_f16 %1, %4, %7, %1\n\t"                   \
                    "v_dot2_f32_f16 %2, %5, %6, %2\n\t"                   \
                    "v_dot2_f32_f16 %3, %5, %7, %3"                       \
                    : "+v"(q0A), "+v"(q1A), "+v"(q0B), "+v"(q1B)          \
                    : "s"(ea[idx]), "s"(eb[idx]),                         \
                      "v"(wk.x), "v"(wk.y));                              \
            }
            KP(0)  KP(1)  KP(2)  KP(3)
            KP(4)  KP(5)  KP(6)  KP(7)
            KP(8)  KP(9)  KP(10) KP(11)
            KP(12) KP(13) KP(14) KP(15)
#undef KP

            q0A += bf2f_lo(psA);
            q1A += bf2f_hi(psA);
            acc0 += fmaxf(q0A, 0.f);
            acc1 += fmaxf(q1A, 0.f);

            q0B += bf2f_lo(psB);
            q1B += bf2f_hi(psB);
            const float m_ = (j + 1 < s1r) ? 1.0f : 0.0f;
            acc0 = fmaf(m_, fmaxf(q0B, 0.f), acc0);
            acc1 = fmaf(m_, fmaxf(q1B, 0.f), acc1);

            psA = psC;
            psB = psD;
        }
#undef PSLD
    }

    const float idg = inv_deg[node];
    *(u32*)(aggZ + (size_t)node * 512 + coff) = packbf2(acc0 * idg, acc1 * idg);
}

// out[node] = dot(h4[node,:], h2w) + h2b  — one wave per node; h4 in Z[:,0:256]
__global__ __launch_bounds__(256) void head_out(
    const u16* __restrict__ h4Z,
    const float* __restrict__ h2w,
    const float* __restrict__ h2b,
    float* __restrict__ out)
{
    const int node = (int)((blockIdx.x * 256 + threadIdx.x) >> 6);
    const int lane = threadIdx.x & 63;
    if (node >= NN) return;
    const int col = lane * 4;
    u16x4 hv = *(const u16x4*)(h4Z + (size_t)node * 512 + col);
    float4 wv = *(const float4*)(h2w + col);
    float s = bf2f(hv[0]) * wv.x + bf2f(hv[1]) * wv.y +
              bf2f(hv[2]) * wv.z + bf2f(hv[3]) * wv.w;
    for (int off = 32; off > 0; off >>= 1)
        s += __shfl_down(s, off, 64);
    if (lane == 0) out[node] = s + h2b[0];
}

// ---------------- setup kernels ----------------
__global__ void zero_int(int* p, int n) {
    int i = blockIdx.x * 256 + threadIdx.x;
    if (i < n) p[i] = 0;
}

__global__ void hist_k(const int* __restrict__ ei, int* __restrict__ deg) {
    int e = blockIdx.x * 256 + threadIdx.x;
    if (e < NE) atomicAdd(&deg[ei[NE + e]], 1);
}

__global__ __launch_bounds__(256) void block_sum_k(const int* __restrict__ deg,
                                                   int* __restrict__ bsum) {
    __shared__ int sm[4];
    const int i = blockIdx.x * 256 + threadIdx.x;
    int v = (i < NN) ? deg[i] : 0;
    for (int off = 32; off > 0; off >>= 1)
        v += __shfl_down(v, off, 64);
    const int lane = threadIdx.x & 63;
    const int w = threadIdx.x >> 6;
    if (lane == 0) sm[w] = v;
    __syncthreads();
    if (threadIdx.x == 0)
        bsum[blockIdx.x] = sm[0] + sm[1] + sm[2] + sm[3];
}

__global__ __launch_bounds__(256) void scan_block_k(const int* __restrict__ bsum,
                                                    int* __restrict__ boff,
                                                    int* __restrict__ row_start) {
    __shared__ int sm[256];
    const int tid = threadIdx.x;
    int v = (tid < NBLK) ? bsum[tid] : 0;
    sm[tid] = v;
    __syncthreads();
    for (int o = 1; o < 256; o <<= 1) {
        int tv = (tid >= o) ? sm[tid - o] : 0;
        __syncthreads();
        sm[tid] += tv;
        __syncthreads();
    }
    if (tid < NBLK) boff[tid] = sm[tid] - v;  // exclusive
    if (tid == NBLK - 1) row_start[NN] = sm[tid];
}

__global__ __launch_bounds__(256) void writeback_k(const int* __restrict__ deg,
                                                   const int* __restrict__ boff,
                                                   int* __restrict__ row_start,
                                                   int* __restrict__ cursor,
                                                   float* __restrict__ inv_deg) {
    __shared__ int sm[256];
    const int tid = threadIdx.x;
    const int i = blockIdx.x * 256 + tid;
    int v = (i < NN) ? deg[i] : 0;
    sm[tid] = v;
    __syncthreads();
    for (int o = 1; o < 256; o <<= 1) {
        int tv = (tid >= o) ? sm[tid - o] : 0;
        __syncthreads();
        sm[tid] += tv;
        __syncthreads();
    }
    if (i < NN) {
        const int rs = boff[blockIdx.x] + sm[tid] - v;
        row_start[i] = rs;
        cursor[i]    = rs;
        inv_deg[i]   = 1.0f / fmaxf((float)v, 1.0f);
    }
}

__global__ void scatter_k(const int* __restrict__ ei, const float* __restrict__ eattr,
                          int* __restrict__ cursor, int* __restrict__ src_perm,
                          u32* __restrict__ eattr_p32) {
    int e = blockIdx.x * 256 + threadIdx.x;
    if (e >= NE) return;
    int s = ei[e], d = ei[NE + e];
    int pos = atomicAdd(&cursor[d], 1);
    src_perm[pos] = s;
    const float* sr = eattr + (size_t)e * 32;
    u32 pk[16];
#pragma unroll
    for (int j = 0; j < 16; ++j)
        pk[j] = packh2(sr[2 * j], sr[2 * j + 1]);
    uint4* dr = (uint4*)(eattr_p32 + (size_t)pos * 16);
    dr[0] = (uint4){pk[0], pk[1], pk[2], pk[3]};
    dr[1] = (uint4){pk[4], pk[5], pk[6], pk[7]};
    dr[2] = (uint4){pk[8], pk[9], pk[10], pk[11]};
    dr[3] = (uint4){pk[12], pk[13], pk[14], pk[15]};
}

// P-GEMM bias: [512] f32 per layer = [0(256) | eb(256)]
__global__ void bias_build(const float* __restrict__ e0b,
                           const float* __restrict__ eb1,
                           const float* __restrict__ eb2,
                           float* __restrict__ dst) {
    int i = blockIdx.x * 256 + threadIdx.x;
    if (i >= 1536) return;
    int l = i >> 9, c = i & 511;
    const float* s = (l == 0) ? e0b : (l == 1) ? eb1 : eb2;
    dst[i] = (c < 256) ? 0.f : s[c - 256];
}

// jobs: tr=1: dst[n*dstride+k] = bf16(src[k*256+n]), n in 0..255, k in 0..K-1
//       tr=2: We pack u32: dst32[kp*256+c] = packh2(src[2kp*256+c], src[(2kp+1)*256+c])
struct TJob { const float* src; u16* dst; int K; int ksh; int tr; int dstride; };
struct TJobs { TJob j[16]; };

__global__ void transpose_k(TJobs jobs) {
    TJob jb = jobs.j[blockIdx.y];
    int idx = blockIdx.x * 256 + threadIdx.x;
    if (idx >= (jb.K << 8)) return;
    if (jb.tr == 1) {
        int n = idx >> jb.ksh;
        int k = idx & (jb.K - 1);
        jb.dst[n * jb.dstride + k] = f2bf(jb.src[k * 256 + n]);
    } else {
        int kp = idx >> 8;
        int c = idx & 255;
        ((u32*)jb.dst)[idx] = packh2(jb.src[(2 * kp) * 256 + c],
                                     jb.src[(2 * kp + 1) * 256 + c]);
    }
}

// x (f32 [NN,128]) -> Z[:,256:384] bf16 (row stride 512)
__global__ void cvt_x(const float* __restrict__ src, u16* __restrict__ Z) {
    int i = blockIdx.x * 256 + threadIdx.x;
    if (i >= NN * 128) return;
    int n = i >> 7, c = i & 127;
    Z[(size_t)n * 512 + 256 + c] = f2bf(src[i]);
}

// ---------------------------------------------------------------------------
extern "C" void kernel_launch(void* const* d_in, const int* in_sizes, int n_in,
                              void* d_out, int out_size, void* d_ws, size_t ws_size,
                              hipStream_t stream) {
    const float* x     = (const float*)d_in[0];
    const int*   ei    = (const int*)d_in[1];
    const float* eattr = (const float*)d_in[2];
    const float* e0_w  = (const float*)d_in[3];
    const float* e0_b  = (const float*)d_in[4];
    const float* n0_w  = (const float*)d_in[5];
    const float* n0_b  = (const float*)d_in[6];
    const float* e_w   = (const float*)d_in[7];
    const float* e_b   = (const float*)d_in[8];
    const float* n_w   = (const float*)d_in[9];
    const float* n_b   = (const float*)d_in[10];
    const float* h1_w  = (const float*)d_in[11];
    const float* h1_b  = (const float*)d_in[12];
    const float* h2_w  = (const float*)d_in[13];
    const float* h2_b  = (const float*)d_in[14];
    float* out = (float*)d_out;
    (void)in_sizes; (void)n_in; (void)out_size; (void)ws_size;

    char* base = (char*)d_ws;
    size_t off = 0;
    auto alloc = [&](size_t nbytes) -> void* {
        void* p = base + off;
        off += (nbytes + 255) & ~(size_t)255;
        return p;
    };

    int*   deg       = (int*)alloc(NN * 4);
    int*   row_start = (int*)alloc((NN + 1) * 4);
    int*   cursor    = (int*)alloc(NN * 4);
    float* invdeg    = (float*)alloc(NN * 4);
    int*   bsum      = (int*)alloc(NBLK * 4);
    int*   boff      = (int*)alloc(NBLK * 4);
    int*   src_perm  = (int*)alloc(NE * 4);
    u32*   eattr_p32 = (u32*)alloc((size_t)NE * 16 * 4);
    u16*   WcatT0    = (u16*)alloc(512 * 128 * 2);
    u16*   WcatT1    = (u16*)alloc(512 * 256 * 2);
    u16*   WcatT2    = (u16*)alloc(512 * 256 * 2);
    u32*   WePk0     = (u32*)alloc(16 * 256 * 4);
    u32*   WePk1     = (u32*)alloc(16 * 256 * 4);
    u32*   WePk2     = (u32*)alloc(16 * 256 * 4);
    u16*   BcatT0    = (u16*)alloc(256 * 384 * 2);
    u16*   BcatT1    = (u16*)alloc(256 * 512 * 2);
    u16*   BcatT2    = (u16*)alloc(256 * 512 * 2);
    u16*   H1T       = (u16*)alloc(256 * 256 * 2);
    float* bias512   = (float*)alloc(3 * 512 * 4);
    u16*   P         = (u16*)alloc((size_t)NN * PST * 2);
    u16*   Z0        = (u16*)alloc((size_t)NN * 512 * 2);
    u16*   Z1        = (u16*)alloc((size_t)NN * 512 * 2);

    // ---- CSR build + weight prep ----
    zero_int<<<(NN + 255) / 256, 256, 0, stream>>>(deg, NN);
    hist_k<<<(NE + 255) / 256, 256, 0, stream>>>(ei, deg);
    block_sum_k<<<NBLK, 256, 0, stream>>>(deg, bsum);
    scan_block_k<<<1, 256, 0, stream>>>(bsum, boff, row_start);
    writeback_k<<<NBLK, 256, 0, stream>>>(deg, boff, row_start, cursor, invdeg);
    scatter_k<<<(NE + 255) / 256, 256, 0, stream>>>(ei, eattr, cursor, src_perm, eattr_p32);
    bias_build<<<6, 256, 0, stream>>>(e0_b, e_b, e_b + 256, bias512);

    const float* ew2 = e_w + 544 * 256;
    const float* nw2 = n_w + 512 * 256;

    TJobs tj;
    auto setj = [&](int i, const float* s, void* d, int K, int tr, int dstride) {
        tj.j[i].src = s; tj.j[i].dst = (u16*)d; tj.j[i].K = K; tj.j[i].tr = tr;
        tj.j[i].dstride = dstride;
        tj.j[i].ksh = (K == 256) ? 8 : (K == 128 ? 7 : 5);
    };
    // P-GEMM weights: WcatT[n(512)][K] = [Ws rows | Wd rows] transposed
    setj(0,  e0_w,             WcatT0,             128, 1, 128);
    setj(1,  e0_w + 128 * 256, WcatT0 + 256 * 128, 128, 1, 128);
    setj(2,  e_w,              WcatT1,             256, 1, 256);
    setj(3,  e_w + 256 * 256,  WcatT1 + 256 * 256, 256, 1, 256);
    setj(4,  ew2,              WcatT2,             256, 1, 256);
    setj(5,  ew2 + 256 * 256,  WcatT2 + 256 * 256, 256, 1, 256);
    // node-GEMM weights: BcatT[n(256)][k] = [nbot(k<256) | ntop]
    setj(6,  n0_w + 128 * 256, BcatT0,             256, 1, 384);
    setj(7,  n0_w,             BcatT0 + 256,       128, 1, 384);
    setj(8,  n_w + 256 * 256,  BcatT1,             256, 1, 512);
    setj(9,  n_w,              BcatT1 + 256,       256, 1, 512);
    setj(10, nw2 + 256 * 256,  BcatT2,             256, 1, 512);
    setj(11, nw2,              BcatT2 + 256,       256, 1, 512);
    setj(12, h1_w,             H1T,                256, 1, 256);
    // edge-attr weights, packed f16 pairs
    setj(13, e0_w + 256 * 256, WePk0,              16,  2, 0);
    setj(14, e_w + 512 * 256,  WePk1,              16,  2, 0);
    setj(15, ew2 + 512 * 256,  WePk2,              16,  2, 0);
    transpose_k<<<dim3(256, 16), 256, 0, stream>>>(tj);

    cvt_x<<<(NN * 128 + 255) / 256, 256, 0, stream>>>(x, Z0);

    const int MT = (NN + 127) / 128;  // 391
    const int AGG_BLK = (2 * NN) / 4;  // 2 waves/node, 4 waves/block = 25000
    u16* WcatT[3] = {WcatT0, WcatT1, WcatT2};
    u32* WePk[3]  = {WePk0, WePk1, WePk2};
    u16* BcatT[3] = {BcatT0, BcatT1, BcatT2};
    const float* nbs[3] = {n0_b, n_b, n_b + 256};
    u16* Zin[3]  = {Z0, Z1, Z0};
    u16* Zout[3] = {Z1, Z0, Z1};
    const int kin[3]   = {128, 256, 256};
    const int knode[3] = {384, 512, 512};

    for (int l = 0; l < 3; ++l) {
        // P = h @ [Ws | Wd] + [0|eb]  -> [NN, 512] (stride PST)
        gemm_bt<<<dim3(MT, 4), 256, 0, stream>>>(Zin[l] + 256, 512, WcatT[l], P, PST,
                                                 NN, kin[l], bias512 + l * 512, 0);
        // agg = mean_dst relu(Ps[src] + Pd[dst] + eattr@We)
        edge_agg_fused<<<AGG_BLK, 256, 0, stream>>>(P, eattr_p32, WePk[l], row_start,
                                                    src_perm, invdeg, Zin[l]);
        // h' = relu([agg | h] @ [nbot; ntop] + nb)
        gemm_bt<<<dim3(MT, 2), 256, 0, stream>>>(Zin[l], 512, BcatT[l], Zout[l] + 256, 512,
                                                 NN, knode[l], nbs[l], 1);
    }
    // head: h4 = relu(h3 @ h1_w + h1_b) -> Z1[:,0:256]; out = h4 @ h2_w + h2_b
    gemm_bt<<<dim3(MT, 2), 256, 0, stream>>>(Z1 + 256, 512, H1T, Z1, 512,
                                             NN, 256, h1_b, 1);
    head_out<<<NN / 4, 256, 0, stream>>>(Z1, h2_w, h2_b, out);
}

// Round 9
// 754.274 us; speedup vs baseline: 1.0533x; 1.0533x over previous
//
#include <hip/hip_runtime.h>
#include <hip/hip_bf16.h>
#include <hip/hip_fp16.h>

#define NN 50000
#define NE 400000
#define NBLK 196   // ceil(NN/256)
#define PST 544    // P row stride (1088 B = 64*17, breaks power-of-2 aliasing)

typedef unsigned short u16;
typedef unsigned int u32;
typedef __attribute__((ext_vector_type(8))) short short8;
typedef __attribute__((ext_vector_type(4))) float f32x4;
typedef __attribute__((ext_vector_type(4))) unsigned short u16x4;
typedef __attribute__((ext_vector_type(2))) _Float16 h2;
typedef __attribute__((ext_vector_type(16))) unsigned int u32x16;

typedef __attribute__((address_space(1))) const void as1_void;
typedef __attribute__((address_space(3))) void as3_void;

static __device__ __forceinline__ float bf2f(u16 u) {
    return __uint_as_float(((u32)u) << 16);
}
static __device__ __forceinline__ float bf2f_lo(u32 u) {
    return __uint_as_float(u << 16);
}
static __device__ __forceinline__ float bf2f_hi(u32 u) {
    return __uint_as_float(u & 0xffff0000u);
}
static __device__ __forceinline__ u16 f2bf(float f) {
    u32 x = __float_as_uint(f);
    x += 0x7fffu + ((x >> 16) & 1u);
    return (u16)(x >> 16);
}
static __device__ __forceinline__ u32 packbf2(float a, float b) {
    return ((u32)f2bf(b) << 16) | (u32)f2bf(a);
}
static __device__ __forceinline__ u32 packh2(float a, float b) {
    return ((u32)__half_as_ushort(__float2half(b)) << 16) |
           (u32)__half_as_ushort(__float2half(a));
}
static __device__ __forceinline__ float fdot2u(u32 a, u32 b, float c) {
    return __builtin_amdgcn_fdot2(__builtin_bit_cast(h2, a),
                                  __builtin_bit_cast(h2, b), c, false);
}

static __device__ __forceinline__ void gload_lds16(const u16* g, u16* l) {
    __builtin_amdgcn_global_load_lds((as1_void*)g, (as3_void*)l, 16, 0, 0);
}

// ---------------------------------------------------------------------------
// bf16 GEMM: C[M,N] = A[M,K] @ Bt[N,K]^T, epilogue (+bias)(relu), bf16 out.
// m97 structure: 128x128 tile, BK=32, 4 waves, 4x4 16x16x32 frags.
// ---------------------------------------------------------------------------
__global__ __launch_bounds__(256) void gemm_bt(
    const u16* __restrict__ A, int lda,
    const u16* __restrict__ Bt,
    u16* __restrict__ C, int ldc,
    int M, int K,
    const float* __restrict__ bias,
    int relu)
{
    __shared__ u16 As[128 * 32];
    __shared__ u16 Bs[128 * 32];

    const int t = threadIdx.x;
    const int w = t >> 6;
    const int lane = t & 63;
    const int quad = lane >> 4;
    const int l15 = lane & 15;
    const int tile_m = blockIdx.x * 128;
    const int tile_n = blockIdx.y * 128;
    const int wm = (w >> 1) * 64;
    const int wn = (w & 1) * 64;

    f32x4 acc[4][4];
#pragma unroll
    for (int r = 0; r < 4; ++r)
#pragma unroll
        for (int c = 0; c < 4; ++c)
            acc[r][c] = (f32x4){0.f, 0.f, 0.f, 0.f};

    int ar0 = tile_m + (t >> 2);      if (ar0 > M - 1) ar0 = M - 1;
    int ar1 = tile_m + 64 + (t >> 2); if (ar1 > M - 1) ar1 = M - 1;
    const int br0 = tile_n + (t >> 2);
    const int br1 = tile_n + 64 + (t >> 2);
    const int koff = (t & 3) * 8;

    u16* lAs0 = As + w * 512;
    u16* lAs1 = As + 2048 + w * 512;
    u16* lBs0 = Bs + w * 512;
    u16* lBs1 = Bs + 2048 + w * 512;

    const u16* Arow0 = A + (size_t)ar0 * lda + koff;
    const u16* Arow1 = A + (size_t)ar1 * lda + koff;
    const u16* Brow0 = Bt + (size_t)br0 * K + koff;
    const u16* Brow1 = Bt + (size_t)br1 * K + koff;

    for (int k0 = 0; k0 < K; k0 += 32) {
        gload_lds16(Arow0 + k0, lAs0);
        gload_lds16(Arow1 + k0, lAs1);
        gload_lds16(Brow0 + k0, lBs0);
        gload_lds16(Brow1 + k0, lBs1);
        __syncthreads();

        short8 af[4], bfr[4];
#pragma unroll
        for (int r = 0; r < 4; ++r)
            af[r] = *(const short8*)&As[(wm + r * 16 + l15) * 32 + quad * 8];
#pragma unroll
        for (int c = 0; c < 4; ++c)
            bfr[c] = *(const short8*)&Bs[(wn + c * 16 + l15) * 32 + quad * 8];
#pragma unroll
        for (int r = 0; r < 4; ++r)
#pragma unroll
            for (int c = 0; c < 4; ++c)
                acc[r][c] = __builtin_amdgcn_mfma_f32_16x16x32_bf16(af[r], bfr[c], acc[r][c], 0, 0, 0);
        __syncthreads();
    }

#pragma unroll
    for (int r = 0; r < 4; ++r) {
#pragma unroll
        for (int c = 0; c < 4; ++c) {
            const int coln = tile_n + wn + c * 16 + l15;
            const float bv = bias ? bias[coln] : 0.0f;
#pragma unroll
            for (int i = 0; i < 4; ++i) {
                const int row = tile_m + wm + r * 16 + quad * 4 + i;
                if (row < M) {
                    float v = acc[r][c][i] + bv;
                    if (relu) v = fmaxf(v, 0.f);
                    C[(size_t)row * ldc + coln] = f2bf(v);
                }
            }
        }
    }
}

// ---------------------------------------------------------------------------
// Fused edge message + mean aggregation. ONE wave per node, 256 cols
// (4 cols/lane as 2 packed-bf16 u32).
//
// Ledger R0-R8: every single-factor change (weight path, eattr path, dot
// encoding, register knobs) was null at ~103us. The consistent model:
// latency-bound at ~1 exposed gather latency per 2-edge trip (390 trips/SIMD
// x ~630cy = measured 247k cy); VALUBusy is ~2x-inflated by the gfx94x
// derived-formula fallback (true issue floor ~34us).
// This version attacks trip count + duplication + in-trip latency:
//  - 1 wave/node: halves wave-edges (no more 2x duplicated eattr reads and
//    gather requests); trips/SIMD 390 -> ~207.
//  - weights amortized across BOTH edges of a trip: 16 ds_read_b128/trip.
//  - eattr via s_load_dwordx16 (scalar pipe, SGPRs); next trip's src
//    indices prefetched under the same lgkm wait.
//  - ps gathers issued at trip top via asm (non-sinkable), consumed AFTER
//    the ~300cy dot block behind a counted vmcnt(0) fence -> gather latency
//    mostly covered in-trip, remainder by 8-wave TLP.
// P rows [Ps(256)|Pd(256)], stride PST. agg -> Z[:,0:256] (stride 512).
// ---------------------------------------------------------------------------
__global__ __launch_bounds__(256) void edge_agg_fused(
    const u16* __restrict__ P,
    const u32* __restrict__ eattr_p32,
    const u32* __restrict__ WePk,
    const int* __restrict__ row_start,
    const int* __restrict__ src_perm,
    const float* __restrict__ inv_deg,
    u16* __restrict__ aggZ)
{
    __shared__ u32 Wlds[4096];   // 16 KB: same linear layout as WePk

    const int t = threadIdx.x;
    {   // stage weights: 4 rounds x (4 waves x 64 lanes x 16 B) = 16 KB
        const u16* Wg = (const u16*)WePk;
        u16* Wl = (u16*)Wlds;
        const int wv = t >> 6;
        const int ln = t & 63;
#pragma unroll
        for (int r = 0; r < 4; ++r)
            gload_lds16(Wg + r * 2048 + wv * 512 + ln * 8,
                        Wl + r * 2048 + wv * 512);
    }
    __syncthreads();

    const int node = (int)((blockIdx.x * 256 + t) >> 6);
    const int lane = t & 63;
    const int c4 = lane * 4;            // first of this lane's 4 cols
    if (node >= NN) return;             // grid exact; after barrier

    const uint2 pdu = *(const uint2*)(P + (size_t)node * PST + 256 + c4);
    const float pb0 = bf2f_lo(pdu.x), pb1 = bf2f_hi(pdu.x);
    const float pb2 = bf2f_lo(pdu.y), pb3 = bf2f_hi(pdu.y);

    float acc0 = 0.f, acc1 = 0.f, acc2 = 0.f, acc3 = 0.f;
    const int s0r = row_start[node], s1r = row_start[node + 1];

    if (s1r > s0r) {
        const int jlast = s1r - 1;
        const unsigned long long ebase =
            (unsigned long long)(uintptr_t)eattr_p32;
        const u32 voff = (u32)(c4 * 2);   // byte offset of lane's cols in a P row

        // src indices for the first trip (scalar loads, compiler-managed)
        int ssA = src_perm[__builtin_amdgcn_readfirstlane(s0r)];
        int ssB = src_perm[__builtin_amdgcn_readfirstlane(
            (s0r + 1 < jlast) ? s0r + 1 : jlast)];

        for (int j = s0r; j < s1r; j += 2) {
            // ps gathers for THIS trip: issued now, consumed after the dots
            const u16* rowpA = P + (size_t)ssA * PST;
            const u16* rowpB = P + (size_t)ssB * PST;
            uint2 psA, psB;
            asm volatile("global_load_dwordx2 %0, %1, %2"
                         : "=v"(psA) : "v"(voff), "s"(rowpA));
            asm volatile("global_load_dwordx2 %0, %1, %2"
                         : "=v"(psB) : "v"(voff), "s"(rowpB));

            // eattr rows for both edges -> SGPR tuples (scalar pipe)
            const u32 offA = (u32)__builtin_amdgcn_readfirstlane(j) << 6;
            const u32 offB = (u32)__builtin_amdgcn_readfirstlane(
                (j + 1 < jlast) ? j + 1 : jlast) << 6;
            u32x16 ea, eb;
            asm volatile("s_load_dwordx16 %0, %2, %3\n\t"
                         "s_load_dwordx16 %1, %2, %4"
                         : "=s"(ea), "=s"(eb)
                         : "s"(ebase), "s"(offA), "s"(offB));

            // prefetch next trip's src indices under the same lgkm wait
            const int jA2 = (j + 2 < jlast) ? j + 2 : jlast;
            const int jB2 = (j + 3 < jlast) ? j + 3 : jlast;
            int ssA_n = src_perm[__builtin_amdgcn_readfirstlane(jA2)];
            int ssB_n = src_perm[__builtin_amdgcn_readfirstlane(jB2)];

            asm volatile("s_waitcnt lgkmcnt(0)" ::: "memory");
            __builtin_amdgcn_sched_barrier(0);

            float qA0 = pb0, qA1 = pb1, qA2 = pb2, qA3 = pb3;
            float qB0 = pb0, qB1 = pb1, qB2 = pb2, qB3 = pb3;
#pragma unroll
            for (int kp = 0; kp < 16; ++kp) {
                uint4 wk = *(const uint4*)(Wlds + kp * 256 + c4);
                qA0 = fdot2u(ea[kp], wk.x, qA0);
                qA1 = fdot2u(ea[kp], wk.y, qA1);
                qA2 = fdot2u(ea[kp], wk.z, qA2);
                qA3 = fdot2u(ea[kp], wk.w, qA3);
                qB0 = fdot2u(eb[kp], wk.x, qB0);
                qB1 = fdot2u(eb[kp], wk.y, qB1);
                qB2 = fdot2u(eb[kp], wk.z, qB2);
                qB3 = fdot2u(eb[kp], wk.w, qB3);
            }

            // ps must have landed (only vmem in loop = our 2 asm loads)
            asm volatile("s_waitcnt vmcnt(0)" ::: "memory");
            __builtin_amdgcn_sched_barrier(0);

            acc0 += fmaxf(qA0 + bf2f_lo(psA.x), 0.f);
            acc1 += fmaxf(qA1 + bf2f_hi(psA.x), 0.f);
            acc2 += fmaxf(qA2 + bf2f_lo(psA.y), 0.f);
            acc3 += fmaxf(qA3 + bf2f_hi(psA.y), 0.f);
            const float mB = (j + 1 < s1r) ? 1.0f : 0.0f;
            acc0 = fmaf(mB, fmaxf(qB0 + bf2f_lo(psB.x), 0.f), acc0);
            acc1 = fmaf(mB, fmaxf(qB1 + bf2f_hi(psB.x), 0.f), acc1);
            acc2 = fmaf(mB, fmaxf(qB2 + bf2f_lo(psB.y), 0.f), acc2);
            acc3 = fmaf(mB, fmaxf(qB3 + bf2f_hi(psB.y), 0.f), acc3);

            ssA = ssA_n;
            ssB = ssB_n;
        }
    }

    const float idg = inv_deg[node];
    uint2 outv;
    outv.x = packbf2(acc0 * idg, acc1 * idg);
    outv.y = packbf2(acc2 * idg, acc3 * idg);
    *(uint2*)(aggZ + (size_t)node * 512 + c4) = outv;
}

// out[node] = dot(h4[node,:], h2w) + h2b  — one wave per node; h4 in Z[:,0:256]
__global__ __launch_bounds__(256) void head_out(
    const u16* __restrict__ h4Z,
    const float* __restrict__ h2w,
    const float* __restrict__ h2b,
    float* __restrict__ out)
{
    const int node = (int)((blockIdx.x * 256 + threadIdx.x) >> 6);
    const int lane = threadIdx.x & 63;
    if (node >= NN) return;
    const int col = lane * 4;
    u16x4 hv = *(const u16x4*)(h4Z + (size_t)node * 512 + col);
    float4 wv = *(const float4*)(h2w + col);
    float s = bf2f(hv[0]) * wv.x + bf2f(hv[1]) * wv.y +
              bf2f(hv[2]) * wv.z + bf2f(hv[3]) * wv.w;
    for (int off = 32; off > 0; off >>= 1)
        s += __shfl_down(s, off, 64);
    if (lane == 0) out[node] = s + h2b[0];
}

// ---------------- setup kernels ----------------
__global__ void zero_int(int* p, int n) {
    int i = blockIdx.x * 256 + threadIdx.x;
    if (i < n) p[i] = 0;
}

__global__ void hist_k(const int* __restrict__ ei, int* __restrict__ deg) {
    int e = blockIdx.x * 256 + threadIdx.x;
    if (e < NE) atomicAdd(&deg[ei[NE + e]], 1);
}

__global__ __launch_bounds__(256) void block_sum_k(const int* __restrict__ deg,
                                                   int* __restrict__ bsum) {
    __shared__ int sm[4];
    const int i = blockIdx.x * 256 + threadIdx.x;
    int v = (i < NN) ? deg[i] : 0;
    for (int off = 32; off > 0; off >>= 1)
        v += __shfl_down(v, off, 64);
    const int lane = threadIdx.x & 63;
    const int w = threadIdx.x >> 6;
    if (lane == 0) sm[w] = v;
    __syncthreads();
    if (threadIdx.x == 0)
        bsum[blockIdx.x] = sm[0] + sm[1] + sm[2] + sm[3];
}

__global__ __launch_bounds__(256) void scan_block_k(const int* __restrict__ bsum,
                                                    int* __restrict__ boff,
                                                    int* __restrict__ row_start) {
    __shared__ int sm[256];
    const int tid = threadIdx.x;
    int v = (tid < NBLK) ? bsum[tid] : 0;
    sm[tid] = v;
    __syncthreads();
    for (int o = 1; o < 256; o <<= 1) {
        int tv = (tid >= o) ? sm[tid - o] : 0;
        __syncthreads();
        sm[tid] += tv;
        __syncthreads();
    }
    if (tid < NBLK) boff[tid] = sm[tid] - v;  // exclusive
    if (tid == NBLK - 1) row_start[NN] = sm[tid];
}

__global__ __launch_bounds__(256) void writeback_k(const int* __restrict__ deg,
                                                   const int* __restrict__ boff,
                                                   int* __restrict__ row_start,
                                                   int* __restrict__ cursor,
                                                   float* __restrict__ inv_deg) {
    __shared__ int sm[256];
    const int tid = threadIdx.x;
    const int i = blockIdx.x * 256 + tid;
    int v = (i < NN) ? deg[i] : 0;
    sm[tid] = v;
    __syncthreads();
    for (int o = 1; o < 256; o <<= 1) {
        int tv = (tid >= o) ? sm[tid - o] : 0;
        __syncthreads();
        sm[tid] += tv;
        __syncthreads();
    }
    if (i < NN) {
        const int rs = boff[blockIdx.x] + sm[tid] - v;
        row_start[i] = rs;
        cursor[i]    = rs;
        inv_deg[i]   = 1.0f / fmaxf((float)v, 1.0f);
    }
}

__global__ void scatter_k(const int* __restrict__ ei, const float* __restrict__ eattr,
                          int* __restrict__ cursor, int* __restrict__ src_perm,
                          u32* __restrict__ eattr_p32) {
    int e = blockIdx.x * 256 + threadIdx.x;
    if (e >= NE) return;
    int s = ei[e], d = ei[NE + e];
    int pos = atomicAdd(&cursor[d], 1);
    src_perm[pos] = s;
    const float* sr = eattr + (size_t)e * 32;
    u32 pk[16];
#pragma unroll
    for (int j = 0; j < 16; ++j)
        pk[j] = packh2(sr[2 * j], sr[2 * j + 1]);
    uint4* dr = (uint4*)(eattr_p32 + (size_t)pos * 16);
    dr[0] = (uint4){pk[0], pk[1], pk[2], pk[3]};
    dr[1] = (uint4){pk[4], pk[5], pk[6], pk[7]};
    dr[2] = (uint4){pk[8], pk[9], pk[10], pk[11]};
    dr[3] = (uint4){pk[12], pk[13], pk[14], pk[15]};
}

// P-GEMM bias: [512] f32 per layer = [0(256) | eb(256)]
__global__ void bias_build(const float* __restrict__ e0b,
                           const float* __restrict__ eb1,
                           const float* __restrict__ eb2,
                           float* __restrict__ dst) {
    int i = blockIdx.x * 256 + threadIdx.x;
    if (i >= 1536) return;
    int l = i >> 9, c = i & 511;
    const float* s = (l == 0) ? e0b : (l == 1) ? eb1 : eb2;
    dst[i] = (c < 256) ? 0.f : s[c - 256];
}

// jobs: tr=1: dst[n*dstride+k] = bf16(src[k*256+n]), n in 0..255, k in 0..K-1
//       tr=2: We pack u32: dst32[kp*256+c] = packh2(src[2kp*256+c], src[(2kp+1)*256+c])
struct TJob { const float* src; u16* dst; int K; int ksh; int tr; int dstride; };
struct TJobs { TJob j[16]; };

__global__ void transpose_k(TJobs jobs) {
    TJob jb = jobs.j[blockIdx.y];
    int idx = blockIdx.x * 256 + threadIdx.x;
    if (idx >= (jb.K << 8)) return;
    if (jb.tr == 1) {
        int n = idx >> jb.ksh;
        int k = idx & (jb.K - 1);
        jb.dst[n * jb.dstride + k] = f2bf(jb.src[k * 256 + n]);
    } else {
        int kp = idx >> 8;
        int c = idx & 255;
        ((u32*)jb.dst)[idx] = packh2(jb.src[(2 * kp) * 256 + c],
                                     jb.src[(2 * kp + 1) * 256 + c]);
    }
}

// x (f32 [NN,128]) -> Z[:,256:384] bf16 (row stride 512)
__global__ void cvt_x(const float* __restrict__ src, u16* __restrict__ Z) {
    int i = blockIdx.x * 256 + threadIdx.x;
    if (i >= NN * 128) return;
    int n = i >> 7, c = i & 127;
    Z[(size_t)n * 512 + 256 + c] = f2bf(src[i]);
}

// ---------------------------------------------------------------------------
extern "C" void kernel_launch(void* const* d_in, const int* in_sizes, int n_in,
                              void* d_out, int out_size, void* d_ws, size_t ws_size,
                              hipStream_t stream) {
    const float* x     = (const float*)d_in[0];
    const int*   ei    = (const int*)d_in[1];
    const float* eattr = (const float*)d_in[2];
    const float* e0_w  = (const float*)d_in[3];
    const float* e0_b  = (const float*)d_in[4];
    const float* n0_w  = (const float*)d_in[5];
    const float* n0_b  = (const float*)d_in[6];
    const float* e_w   = (const float*)d_in[7];
    const float* e_b   = (const float*)d_in[8];
    const float* n_w   = (const float*)d_in[9];
    const float* n_b   = (const float*)d_in[10];
    const float* h1_w  = (const float*)d_in[11];
    const float* h1_b  = (const float*)d_in[12];
    const float* h2_w  = (const float*)d_in[13];
    const float* h2_b  = (const float*)d_in[14];
    float* out = (float*)d_out;
    (void)in_sizes; (void)n_in; (void)out_size; (void)ws_size;

    char* base = (char*)d_ws;
    size_t off = 0;
    auto alloc = [&](size_t nbytes) -> void* {
        void* p = base + off;
        off += (nbytes + 255) & ~(size_t)255;
        return p;
    };

    int*   deg       = (int*)alloc(NN * 4);
    int*   row_start = (int*)alloc((NN + 1) * 4);
    int*   cursor    = (int*)alloc(NN * 4);
    float* invdeg    = (float*)alloc(NN * 4);
    int*   bsum      = (int*)alloc(NBLK * 4);
    int*   boff      = (int*)alloc(NBLK * 4);
    int*   src_perm  = (int*)alloc(NE * 4);
    u32*   eattr_p32 = (u32*)alloc((size_t)NE * 16 * 4);
    u16*   WcatT0    = (u16*)alloc(512 * 128 * 2);
    u16*   WcatT1    = (u16*)alloc(512 * 256 * 2);
    u16*   WcatT2    = (u16*)alloc(512 * 256 * 2);
    u32*   WePk0     = (u32*)alloc(16 * 256 * 4);
    u32*   WePk1     = (u32*)alloc(16 * 256 * 4);
    u32*   WePk2     = (u32*)alloc(16 * 256 * 4);
    u16*   BcatT0    = (u16*)alloc(256 * 384 * 2);
    u16*   BcatT1    = (u16*)alloc(256 * 512 * 2);
    u16*   BcatT2    = (u16*)alloc(256 * 512 * 2);
    u16*   H1T       = (u16*)alloc(256 * 256 * 2);
    float* bias512   = (float*)alloc(3 * 512 * 4);
    u16*   P         = (u16*)alloc((size_t)NN * PST * 2);
    u16*   Z0        = (u16*)alloc((size_t)NN * 512 * 2);
    u16*   Z1        = (u16*)alloc((size_t)NN * 512 * 2);

    // ---- CSR build + weight prep ----
    zero_int<<<(NN + 255) / 256, 256, 0, stream>>>(deg, NN);
    hist_k<<<(NE + 255) / 256, 256, 0, stream>>>(ei, deg);
    block_sum_k<<<NBLK, 256, 0, stream>>>(deg, bsum);
    scan_block_k<<<1, 256, 0, stream>>>(bsum, boff, row_start);
    writeback_k<<<NBLK, 256, 0, stream>>>(deg, boff, row_start, cursor, invdeg);
    scatter_k<<<(NE + 255) / 256, 256, 0, stream>>>(ei, eattr, cursor, src_perm, eattr_p32);
    bias_build<<<6, 256, 0, stream>>>(e0_b, e_b, e_b + 256, bias512);

    const float* ew2 = e_w + 544 * 256;
    const float* nw2 = n_w + 512 * 256;

    TJobs tj;
    auto setj = [&](int i, const float* s, void* d, int K, int tr, int dstride) {
        tj.j[i].src = s; tj.j[i].dst = (u16*)d; tj.j[i].K = K; tj.j[i].tr = tr;
        tj.j[i].dstride = dstride;
        tj.j[i].ksh = (K == 256) ? 8 : (K == 128 ? 7 : 5);
    };
    // P-GEMM weights: WcatT[n(512)][K] = [Ws rows | Wd rows] transposed
    setj(0,  e0_w,             WcatT0,             128, 1, 128);
    setj(1,  e0_w + 128 * 256, WcatT0 + 256 * 128, 128, 1, 128);
    setj(2,  e_w,              WcatT1,             256, 1, 256);
    setj(3,  e_w + 256 * 256,  WcatT1 + 256 * 256, 256, 1, 256);
    setj(4,  ew2,              WcatT2,             256, 1, 256);
    setj(5,  ew2 + 256 * 256,  WcatT2 + 256 * 256, 256, 1, 256);
    // node-GEMM weights: BcatT[n(256)][k] = [nbot(k<256) | ntop]
    setj(6,  n0_w + 128 * 256, BcatT0,             256, 1, 384);
    setj(7,  n0_w,             BcatT0 + 256,       128, 1, 384);
    setj(8,  n_w + 256 * 256,  BcatT1,             256, 1, 512);
    setj(9,  n_w,              BcatT1 + 256,       256, 1, 512);
    setj(10, nw2 + 256 * 256,  BcatT2,             256, 1, 512);
    setj(11, nw2,              BcatT2 + 256,       256, 1, 512);
    setj(12, h1_w,             H1T,                256, 1, 256);
    // edge-attr weights, packed f16 pairs
    setj(13, e0_w + 256 * 256, WePk0,              16,  2, 0);
    setj(14, e_w + 512 * 256,  WePk1,              16,  2, 0);
    setj(15, ew2 + 512 * 256,  WePk2,              16,  2, 0);
    transpose_k<<<dim3(256, 16), 256, 0, stream>>>(tj);

    cvt_x<<<(NN * 128 + 255) / 256, 256, 0, stream>>>(x, Z0);

    const int MT = (NN + 127) / 128;  // 391
    const int AGG_BLK = NN / 4;       // 1 wave/node, 4 waves/block = 12500
    u16* WcatT[3] = {WcatT0, WcatT1, WcatT2};
    u32* WePk[3]  = {WePk0, WePk1, WePk2};
    u16* BcatT[3] = {BcatT0, BcatT1, BcatT2};
    const float* nbs[3] = {n0_b, n_b, n_b + 256};
    u16* Zin[3]  = {Z0, Z1, Z0};
    u16* Zout[3] = {Z1, Z0, Z1};
    const int kin[3]   = {128, 256, 256};
    const int knode[3] = {384, 512, 512};

    for (int l = 0; l < 3; ++l) {
        // P = h @ [Ws | Wd] + [0|eb]  -> [NN, 512] (stride PST)
        gemm_bt<<<dim3(MT, 4), 256, 0, stream>>>(Zin[l] + 256, 512, WcatT[l], P, PST,
                                                 NN, kin[l], bias512 + l * 512, 0);
        // agg = mean_dst relu(Ps[src] + Pd[dst] + eattr@We)
        edge_agg_fused<<<AGG_BLK, 256, 0, stream>>>(P, eattr_p32, WePk[l], row_start,
                                                    src_perm, invdeg, Zin[l]);
        // h' = relu([agg | h] @ [nbot; ntop] + nb)
        gemm_bt<<<dim3(MT, 2), 256, 0, stream>>>(Zin[l], 512, BcatT[l], Zout[l] + 256, 512,
                                                 NN, knode[l], nbs[l], 1);
    }
    // head: h4 = relu(h3 @ h1_w + h1_b) -> Z1[:,0:256]; out = h4 @ h2_w + h2_b
    gemm_bt<<<dim3(MT, 2), 256, 0, stream>>>(Z1 + 256, 512, H1T, Z1, 512,
                                             NN, 256, h1_b, 1);
    head_out<<<NN / 4, 256, 0, stream>>>(Z1, h2_w, h2_b, out);
}